// Round 1
// 2260.596 us; speedup vs baseline: 1.8515x; 1.8515x over previous
//
#include <hip/hip_runtime.h>
#include <math.h>

// GPT-2 forward, 12 layers, L=1024, D=768, H=12, d=64.
// v2: all GEMMs in BT form (A[M][K] @ B[N][K]^T), bf16 operands in global,
// global_load_lds width-16 staging into linear LDS with XOR source-swizzle
// (conflict-free ds_read_b128), BK=64 -> 8 MFMA per barrier pair.
// Weights transposed+converted to bf16 per layer; activations written bf16
// at producers (same rounding points as v1's in-GEMM conversion -> numerics
// preserved). Residual x stays fp32. Logits grid m-fastest for B-panel reuse.

#define SEQ 1024
#define DMODEL 768
#define NHEADS 12
#define HEADD 64
#define ATT_SCALE 0.125f  // 1/sqrt(64)

typedef unsigned short u16;
typedef __bf16 bf16x8 __attribute__((ext_vector_type(8)));
typedef float f32x4 __attribute__((ext_vector_type(4)));

__device__ __forceinline__ u16 bf(float f) {
    return __builtin_bit_cast(u16, (__bf16)f);  // RNE, compiler emits v_cvt_pk
}

__device__ __forceinline__ void gll16(const u16* g, u16* l) {
    // async global(16B/lane) -> LDS; dest is wave-uniform base + lane*16
    __builtin_amdgcn_global_load_lds(
        (const __attribute__((address_space(1))) unsigned int*)g,
        (__attribute__((address_space(3))) unsigned int*)l, 16, 0, 0);
}

// ---------------------------------------------------------------------------
// BT GEMM: C[M=1024][N] (=, bf16=, or +=) A[M][K] @ B[N][K]^T (+bias, GELU).
// A,B bf16 row-major. Tile 64x64, BK=64, 256 thr = 4 waves.
// grid = (16 m-tiles [fastest], N/64 n-tiles, batch) -> consecutive blocks
// share a B panel (L2/LLC reuse).
// LDS: linear [64][64] bf16 (128B rows), staged by 4x global_load_lds.
//   dest(row,slot16B): row = t>>3 (+32/issue), slot = t&7
//   source col pre-swizzled: slot_g = slot ^ (row&7)  (involution)
//   frag reads XOR the same: conflict-free (2 lanes / 4-bank group).
// Fragments (gfx950, HW-verified m89/m91):
//   A: m=lane&15, k=quad*8+j ; B: n=lane&15, k=quad*8+j ; D: col=lane&15, row=quad*4+r
// MODE: 0 = fp32 store, 1 = bf16 store, 2 = fp32 accumulate.
// BOUND: clamp B rows + guard C cols (logits N=50257 ragged).
// M, K multiples of 64 at every call site.
// ---------------------------------------------------------------------------
template <int MODE, bool GELU, bool BOUND>
__global__ __launch_bounds__(256) void gemm_bt(
    const u16* __restrict__ A, int lda, long aBatch,
    const u16* __restrict__ B, int ldb, long bBatch,
    void* __restrict__ Cv, int ldc, long cBatch,
    const float* __restrict__ bias, int N, int K) {
    __shared__ alignas(16) u16 As[64 * 64];
    __shared__ alignas(16) u16 Bs[64 * 64];

    const int z = blockIdx.z;
    A += (long)z * aBatch;
    B += (long)z * bBatch;

    const int m0 = blockIdx.x * 64;   // m fastest-varying
    const int n0 = blockIdx.y * 64;
    const int t = threadIdx.x;

    const int srow = t >> 3;                          // 0..31 (issue adds 32)
    const int scol = ((t & 7) ^ (srow & 7)) << 3;     // swizzled k-offset (elems)

    const u16* aSrc0 = A + (long)(m0 + srow) * lda + scol;
    const u16* aSrc1 = A + (long)(m0 + srow + 32) * lda + scol;
    int br0 = n0 + srow, br1 = n0 + srow + 32;
    if (BOUND) {
        if (br0 > N - 1) br0 = N - 1;
        if (br1 > N - 1) br1 = N - 1;
    }
    const u16* bSrc0 = B + (long)br0 * ldb + scol;
    const u16* bSrc1 = B + (long)br1 * ldb + scol;

    u16* aDst = &As[t * 8];
    u16* bDst = &Bs[t * 8];

    const int lane = t & 63, w = t >> 6;
    const int quad = lane >> 4, ml = lane & 15;
    const int sw = ml & 7;                 // row&7 for this lane's frag rows
    const int arow64 = (w * 16 + ml) * 64;

    f32x4 acc[4] = {f32x4{0, 0, 0, 0}, f32x4{0, 0, 0, 0},
                    f32x4{0, 0, 0, 0}, f32x4{0, 0, 0, 0}};

    for (int k0 = 0; k0 < K; k0 += 64) {
        if (k0) __syncthreads();           // prior reads done before overwrite
        gll16(aSrc0, aDst);
        gll16(aSrc1, aDst + 2048);
        gll16(bSrc0, bDst);
        gll16(bSrc1, bDst + 2048);
        aSrc0 += 64; aSrc1 += 64; bSrc0 += 64; bSrc1 += 64;
        __syncthreads();                   // drains vmcnt(0) -> LDS valid

        bf16x8 a0 = *(const bf16x8*)&As[arow64 + ((quad ^ sw) << 3)];
        bf16x8 a1 = *(const bf16x8*)&As[arow64 + (((4 + quad) ^ sw) << 3)];
#pragma unroll
        for (int i = 0; i < 4; ++i) {
            const int brow64 = (i * 16 + ml) * 64;
            bf16x8 b0 = *(const bf16x8*)&Bs[brow64 + ((quad ^ sw) << 3)];
            bf16x8 b1 = *(const bf16x8*)&Bs[brow64 + (((4 + quad) ^ sw) << 3)];
            acc[i] = __builtin_amdgcn_mfma_f32_16x16x32_bf16(a0, b0, acc[i], 0, 0, 0);
            acc[i] = __builtin_amdgcn_mfma_f32_16x16x32_bf16(a1, b1, acc[i], 0, 0, 0);
        }
    }

    float* Cf = (float*)Cv + (MODE != 1 ? (long)z * cBatch : 0);
    u16*   Ch = (u16*)Cv  + (MODE == 1 ? (long)z * cBatch : 0);
    const int mrow = m0 + w * 16 + quad * 4;
#pragma unroll
    for (int i = 0; i < 4; ++i) {
        const int col = n0 + i * 16 + ml;
        if (BOUND && col >= N) continue;
        const float bv = bias ? bias[col] : 0.f;
#pragma unroll
        for (int r = 0; r < 4; ++r) {
            float v = acc[i][r] + bv;
            if (GELU) {
                v = 0.5f * v * (1.f + tanhf(0.7978845608028654f * (v + 0.044715f * v * v * v)));
            }
            const long idx = (long)(mrow + r) * ldc + col;
            if (MODE == 0)      Cf[idx] = v;
            else if (MODE == 1) Ch[idx] = bf(v);
            else                Cf[idx] += v;
        }
    }
}

// ---------------------------------------------------------------------------
// Per-layer weight transpose+convert: fp32 [K][N] -> bf16 [N][K], all 4
// matrices of one layer in a single launch (1728 blocks of 64x64 tiles).
// ---------------------------------------------------------------------------
__global__ __launch_bounds__(256) void wtrans4_kernel(
    const float* __restrict__ aw, const float* __restrict__ apw,
    const float* __restrict__ fw, const float* __restrict__ pw,
    u16* __restrict__ awT, u16* __restrict__ apwT,
    u16* __restrict__ fwT, u16* __restrict__ pwT) {
    int b = blockIdx.x;
    const float* src; u16* dst; int K, N;
    if (b < 432)       { src = aw;  dst = awT;  K = 768;  N = 2304; }
    else if (b < 576)  { src = apw; dst = apwT; K = 768;  N = 768;  b -= 432; }
    else if (b < 1152) { src = fw;  dst = fwT;  K = 768;  N = 3072; b -= 576; }
    else               { src = pw;  dst = pwT;  K = 3072; N = 768;  b -= 1152; }
    const int ntn = N >> 6;
    const int n0 = (b % ntn) << 6, k0 = (b / ntn) << 6;

    __shared__ u16 tile[64][68];           // +4 pad: transposed reads 2-way max
    const int t = threadIdx.x, r = t >> 2, c0 = (t & 3) << 4;

    const float* srow = src + (long)(k0 + r) * N + n0 + c0;
    u16* trow = &tile[r][c0];
#pragma unroll
    for (int j = 0; j < 16; ++j) trow[j] = bf(srow[j]);
    __syncthreads();

    alignas(16) u16 tmp[16];
#pragma unroll
    for (int j = 0; j < 16; ++j) tmp[j] = tile[c0 + j][r];
    u16* drow = dst + (long)(n0 + r) * K + k0 + c0;
    *(uint4*)drow       = *(const uint4*)tmp;
    *(uint4*)(drow + 8) = *(const uint4*)(tmp + 8);
}

// V slice of qkv -> vT[h][d][t] (bf16) so PV runs in BT form.
__global__ __launch_bounds__(256) void vtrans_kernel(
    const u16* __restrict__ qkvb, u16* __restrict__ vT) {
    const int t0 = blockIdx.x << 6, h = blockIdx.y;
    __shared__ u16 tile[64][68];
    const int t = threadIdx.x, r = t >> 2, c0 = (t & 3) << 4;
    const u16* srow = qkvb + (long)(t0 + r) * (3 * DMODEL) + 2 * DMODEL + h * HEADD + c0;
#pragma unroll
    for (int j = 0; j < 16; ++j) tile[r][c0 + j] = srow[j];
    __syncthreads();
    alignas(16) u16 tmp[16];
#pragma unroll
    for (int j = 0; j < 16; ++j) tmp[j] = tile[c0 + j][r];
    u16* drow = vT + ((long)h * HEADD + r) * SEQ + t0 + c0;
    *(uint4*)drow       = *(const uint4*)tmp;
    *(uint4*)(drow + 8) = *(const uint4*)(tmp + 8);
}

// fp32 -> bf16 bulk convert (wte for the logits GEMM), 8 elems/thread/iter.
__global__ __launch_bounds__(256) void cvt_bf16_kernel(
    const float* __restrict__ src, u16* __restrict__ dst, long n8) {
    const float4* sp = (const float4*)src;
    for (long i = blockIdx.x * 256 + threadIdx.x; i < n8; i += (long)gridDim.x * 256) {
        const float4 a = sp[2 * i], b = sp[2 * i + 1];
        alignas(16) u16 o[8] = {bf(a.x), bf(a.y), bf(a.z), bf(a.w),
                                bf(b.x), bf(b.y), bf(b.z), bf(b.w)};
        ((uint4*)dst)[i] = *(const uint4*)o;
    }
}

// ---------------------------------------------------------------------------
// Reductions (block = 256 = 4 waves)
// ---------------------------------------------------------------------------
__device__ inline float wave_sum(float v) {
#pragma unroll
    for (int o = 32; o > 0; o >>= 1) v += __shfl_xor(v, o, 64);
    return v;
}
__device__ inline float wave_max(float v) {
#pragma unroll
    for (int o = 32; o > 0; o >>= 1) v = fmaxf(v, __shfl_xor(v, o, 64));
    return v;
}
__device__ inline float block_sum(float v, float* red) {
    v = wave_sum(v);
    if ((threadIdx.x & 63) == 0) red[threadIdx.x >> 6] = v;
    __syncthreads();
    v = red[0] + red[1] + red[2] + red[3];
    __syncthreads();
    return v;
}
__device__ inline float block_max(float v, float* red) {
    v = wave_max(v);
    if ((threadIdx.x & 63) == 0) red[threadIdx.x >> 6] = v;
    __syncthreads();
    v = fmaxf(fmaxf(red[0], red[1]), fmaxf(red[2], red[3]));
    __syncthreads();
    return v;
}

// embed: x[l][d] = wte[ids[l]][d] + wpe[l][d]  (fp32 residual stream)
__global__ __launch_bounds__(256) void embed_kernel(
    const int* __restrict__ ids, const float* __restrict__ wte,
    const float* __restrict__ wpe, float* __restrict__ x) {
    const int l = blockIdx.x;
    const long wo = (long)ids[l] * DMODEL;
    const long po = (long)l * DMODEL;
#pragma unroll
    for (int j = 0; j < 3; ++j) {
        const int d = threadIdx.x + j * 256;
        x[po + d] = wte[wo + d] + wpe[po + d];
    }
}

// LayerNorm, fp32 in -> bf16 out (all LN consumers are GEMM A operands)
__global__ __launch_bounds__(256) void ln_kernel(
    const float* __restrict__ x, const float* __restrict__ g,
    const float* __restrict__ b, u16* __restrict__ out) {
    __shared__ float red[4];
    const int row = blockIdx.x;
    const float* xr = x + (long)row * DMODEL;
    const int t = threadIdx.x;
    float v0 = xr[t], v1 = xr[t + 256], v2 = xr[t + 512];
    const float mean = block_sum(v0 + v1 + v2, red) * (1.f / DMODEL);
    const float d0 = v0 - mean, d1 = v1 - mean, d2 = v2 - mean;
    const float var = block_sum(d0 * d0 + d1 * d1 + d2 * d2, red) * (1.f / DMODEL);
    const float inv = rsqrtf(var + 1e-5f);
    u16* orow = out + (long)row * DMODEL;
    orow[t]       = bf(d0 * inv * g[t]       + b[t]);
    orow[t + 256] = bf(d1 * inv * g[t + 256] + b[t + 256]);
    orow[t + 512] = bf(d2 * inv * g[t + 512] + b[t + 512]);
}

// Single-pass causal softmax: row (h,l) of fp32 scores -> bf16 P.
// One float4 per thread holds the whole 1024-wide row in registers.
__global__ __launch_bounds__(256) void softmax_kernel(
    const float* __restrict__ scores, u16* __restrict__ P) {
    __shared__ float red[4];
    const int l = blockIdx.x, h = blockIdx.y;
    const long row = (long)h * SEQ + l;
    const float4 s4 = ((const float4*)(scores + row * SEQ))[threadIdx.x];
    const int base = threadIdx.x * 4;
    const float e0 = (base + 0 <= l) ? s4.x * ATT_SCALE : -1e30f;
    const float e1 = (base + 1 <= l) ? s4.y * ATT_SCALE : -1e30f;
    const float e2 = (base + 2 <= l) ? s4.z * ATT_SCALE : -1e30f;
    const float e3 = (base + 3 <= l) ? s4.w * ATT_SCALE : -1e30f;
    const float mx = block_max(fmaxf(fmaxf(e0, e1), fmaxf(e2, e3)), red);
    const float p0 = expf(e0 - mx), p1 = expf(e1 - mx);   // masked -> exp(-huge)=0
    const float p2 = expf(e2 - mx), p3 = expf(e3 - mx);
    const float inv = 1.f / block_sum(p0 + p1 + p2 + p3, red);
    alignas(8) u16 o[4] = {bf(p0 * inv), bf(p1 * inv), bf(p2 * inv), bf(p3 * inv)};
    *(uint2*)(P + row * SEQ + base) = *(const uint2*)o;
}

// ---------------------------------------------------------------------------
extern "C" void kernel_launch(void* const* d_in, const int* in_sizes, int n_in,
                              void* d_out, int out_size, void* d_ws, size_t ws_size,
                              hipStream_t stream) {
    const int* input_ids = (const int*)d_in[0];
    // d_in[1]=start_pos(=0), d_in[2]=block_ids(identity), d_in[3,4]=kv pools: unused
    const float* wte     = (const float*)d_in[5];
    const float* wpe     = (const float*)d_in[6];
    const float* ln1_g   = (const float*)d_in[7];
    const float* ln1_b   = (const float*)d_in[8];
    const float* attn_w  = (const float*)d_in[9];
    const float* attn_b  = (const float*)d_in[10];
    const float* attn_pw = (const float*)d_in[11];
    const float* attn_pb = (const float*)d_in[12];
    const float* ln2_g   = (const float*)d_in[13];
    const float* ln2_b   = (const float*)d_in[14];
    const float* fc_w    = (const float*)d_in[15];
    const float* fc_b    = (const float*)d_in[16];
    const float* proj_w  = (const float*)d_in[17];
    const float* proj_b  = (const float*)d_in[18];
    const float* lnf_g   = (const float*)d_in[19];
    const float* lnf_b   = (const float*)d_in[20];

    // workspace carve (~108 MB). wteBF aliases the scores/P/attno/fcact
    // region (83.4 MB >= 77.2 MB), all dead by logits time.
    char* p = (char*)d_ws;
    auto carve = [&](long bytes) { char* q = p; p += (bytes + 255) & ~255L; return q; };
    float* x     = (float*)carve((long)SEQ * DMODEL * 4);          // fp32 residual
    u16*  hbf    = (u16*)carve((long)SEQ * DMODEL * 2);            // LN out (bf16)
    u16*  qkvb   = (u16*)carve((long)SEQ * 3 * DMODEL * 2);        // qkv (bf16)
    u16*  vT     = (u16*)carve((long)NHEADS * HEADD * SEQ * 2);    // V^T (bf16)
    u16*  awT    = (u16*)carve((long)2304 * 768 * 2);
    u16*  apwT   = (u16*)carve((long)768 * 768 * 2);
    u16*  fwT    = (u16*)carve((long)3072 * 768 * 2);
    u16*  pwT    = (u16*)carve((long)768 * 3072 * 2);
    char* region = p;
    float* scores = (float*)carve((long)NHEADS * SEQ * SEQ * 4);   // 50.3 MB
    u16*  P      = (u16*)carve((long)NHEADS * SEQ * SEQ * 2);      // 25.2 MB
    u16*  attno  = (u16*)carve((long)SEQ * DMODEL * 2);
    u16*  fcact  = (u16*)carve((long)SEQ * 4 * DMODEL * 2);
    u16*  wteBF  = (u16*)region;                                   // alias (77.2 MB)

    embed_kernel<<<SEQ, 256, 0, stream>>>(input_ids, wte, wpe, x);

    for (int i = 0; i < 12; ++i) {
        const float* aw  = attn_w  + (long)i * DMODEL * 3 * DMODEL;
        const float* ab  = attn_b  + (long)i * 3 * DMODEL;
        const float* apw = attn_pw + (long)i * DMODEL * DMODEL;
        const float* apb = attn_pb + (long)i * DMODEL;
        const float* fw  = fc_w    + (long)i * DMODEL * 4 * DMODEL;
        const float* fb  = fc_b    + (long)i * 4 * DMODEL;
        const float* pw  = proj_w  + (long)i * 4 * DMODEL * DMODEL;
        const float* pb  = proj_b  + (long)i * DMODEL;

        // bf16-transpose this layer's 4 weight matrices (one launch)
        wtrans4_kernel<<<1728, 256, 0, stream>>>(aw, apw, fw, pw, awT, apwT, fwT, pwT);

        // h = LN1(x)  (bf16)
        ln_kernel<<<SEQ, 256, 0, stream>>>(x, ln1_g + i * DMODEL, ln1_b + i * DMODEL, hbf);
        // qkv = h @ attn_w + attn_b  -> bf16 [1024, 2304]
        gemm_bt<1, false, false><<<dim3(16, 36, 1), 256, 0, stream>>>(
            hbf, DMODEL, 0, awT, DMODEL, 0, qkvb, 3 * DMODEL, 0, ab, 3 * DMODEL, DMODEL);
        // vT[h][d][t] = V
        vtrans_kernel<<<dim3(16, NHEADS), 256, 0, stream>>>(qkvb, vT);
        // scores[h] = Q_h @ K_h^T (fp32), batched over heads
        gemm_bt<0, false, false><<<dim3(16, 16, NHEADS), 256, 0, stream>>>(
            qkvb, 3 * DMODEL, HEADD, qkvb + DMODEL, 3 * DMODEL, HEADD,
            scores, SEQ, (long)SEQ * SEQ, nullptr, SEQ, HEADD);
        // P = causal softmax(scores / 8) (bf16, zero past diagonal)
        softmax_kernel<<<dim3(SEQ, NHEADS), 256, 0, stream>>>(scores, P);
        // attno[:, h*64:] = P_h @ V_h  (via vT, BT form) -> bf16
        gemm_bt<1, false, false><<<dim3(16, 1, NHEADS), 256, 0, stream>>>(
            P, SEQ, (long)SEQ * SEQ, vT, SEQ, (long)HEADD * SEQ,
            attno, DMODEL, HEADD, nullptr, HEADD, SEQ);
        // x += attno @ attn_pw + attn_pb
        gemm_bt<2, false, false><<<dim3(16, 12, 1), 256, 0, stream>>>(
            attno, DMODEL, 0, apwT, DMODEL, 0, x, DMODEL, 0, apb, DMODEL, DMODEL);
        // h = LN2(x)
        ln_kernel<<<SEQ, 256, 0, stream>>>(x, ln2_g + i * DMODEL, ln2_b + i * DMODEL, hbf);
        // fcact = gelu(h @ fc_w + fc_b) -> bf16 [1024, 3072]
        gemm_bt<1, true, false><<<dim3(16, 48, 1), 256, 0, stream>>>(
            hbf, DMODEL, 0, fwT, DMODEL, 0, fcact, 4 * DMODEL, 0, fb, 4 * DMODEL, DMODEL);
        // x += fcact @ proj_w + proj_b
        gemm_bt<2, false, false><<<dim3(16, 12, 1), 256, 0, stream>>>(
            fcact, 4 * DMODEL, 0, pwT, 4 * DMODEL, 0, x, DMODEL, 0, pb, DMODEL, 4 * DMODEL);
    }

    // h = LN_f(x); wteBF = bf16(wte); logits = h @ wte^T -> d_out (fp32)
    ln_kernel<<<SEQ, 256, 0, stream>>>(x, lnf_g, lnf_b, hbf);
    cvt_bf16_kernel<<<2048, 256, 0, stream>>>(wte, wteBF, (long)50257 * 768 / 8);
    gemm_bt<0, false, true><<<dim3(16, 786, 1), 256, 0, stream>>>(
        hbf, DMODEL, 0, wteBF, DMODEL, 0, (float*)d_out, 50257, 0, nullptr, 50257, DMODEL);
}